// Round 4
// baseline (241.622 us; speedup 1.0000x reference)
//
#include <hip/hip_runtime.h>

// ExtractTensorPatches: x (16,3,512,512) f32, window 16x16, stride 8x8, pad 0.
// out (16, 63*63, 3, 16, 16) f32.
// Pure memory movement: ~195 MB write + ~50 MB read -> memory-bound, ~39 us floor.

#define BB 16
#define CC 3
#define HH 512
#define WW 512
#define NH 63
#define NW 63
#define NP (NH * NW)           // 3969 patches per image
// total output float4s: BB * NP * CC * 16 * 4 = 12,192,768
#define TOTAL4 (BB * NP * CC * 16 * 4)

__global__ __launch_bounds__(256) void extract_patches_kernel(
    const float* __restrict__ x, float* __restrict__ out) {
  unsigned int idx = blockIdx.x * 256u + threadIdx.x;  // float4 index into out
  if (idx >= (unsigned int)TOTAL4) return;

  // Decompose: idx = ((((b*NP + p)*CC + c)*16 + i)*4 + j4)
  unsigned int j4 = idx & 3u;          // which float4 within the 16-wide row
  unsigned int t  = idx >> 2;
  unsigned int i  = t & 15u;           // row within window
  t >>= 4;
  unsigned int c  = t % CC;
  t /= CC;
  unsigned int p  = t % NP;
  unsigned int b  = t / NP;
  unsigned int ph = p / NW;
  unsigned int pw = p % NW;

  unsigned int row = ph * 8u + i;
  unsigned int col = pw * 8u + j4 * 4u;     // multiple of 4 -> 16B aligned

  const float4* src = reinterpret_cast<const float4*>(
      x + (((size_t)(b * CC + c) * HH + row) * WW + col));
  reinterpret_cast<float4*>(out)[idx] = *src;
}

extern "C" void kernel_launch(void* const* d_in, const int* in_sizes, int n_in,
                              void* d_out, int out_size, void* d_ws, size_t ws_size,
                              hipStream_t stream) {
  const float* x = (const float*)d_in[0];
  float* out = (float*)d_out;
  dim3 grid((TOTAL4 + 255) / 256);
  extract_patches_kernel<<<grid, 256, 0, stream>>>(x, out);
}

// Round 5
// 226.104 us; speedup vs baseline: 1.0686x; 1.0686x over previous
//
#include <hip/hip_runtime.h>

// ExtractTensorPatches: x (16,3,512,512) f32, window 16x16, stride 8x8, pad 0.
// out (16, 63*63, 3, 16, 16) f32.
//
// Strategy: block = (b, c, ph). Stage 16 input rows (one contiguous 32 KB
// region) into LDS, then emit the 63 patches of that strip with fully
// coalesced 1 KB-per-wave stores. Converts the previous kernel's scattered
// 64B-segment reads (2KB stride, line-straddling, cross-XCD reuse loss) into
// one linear read per block. Output is write-once -> nontemporal stores to
// avoid evicting reused input rows from L2.

#define BB 16
#define CC 3
#define HH 512
#define WW 512
#define NH 63
#define NW 63
#define NP (NH * NW)
#define WIN 16
#define STR 8
#define LDSW 520  // padded LDS row stride in floats: 16B-aligned, 520%32=8 breaks bank cycling

typedef float f4 __attribute__((ext_vector_type(4)));

__global__ __launch_bounds__(256) void extract_patches_lds(
    const float* __restrict__ x, float* __restrict__ out) {
  __shared__ float lds[WIN * LDSW];  // 33,280 B

  unsigned int blk = blockIdx.x;          // (b, c, ph)
  unsigned int ph = blk % NH;
  unsigned int t2 = blk / NH;
  unsigned int c  = t2 % CC;
  unsigned int b  = t2 / CC;
  unsigned int tid = threadIdx.x;

  // ---- Stage: rows [ph*8, ph*8+16) of x[b][c] — 16*512 floats, contiguous.
  const f4* src = reinterpret_cast<const f4*>(
      x + (((size_t)(b * CC + c) * HH + ph * STR) * WW));
  #pragma unroll
  for (int k = 0; k < 8; ++k) {
    unsigned int idx  = tid + k * 256u;   // float4 index within the 32 KB strip
    f4 v = src[idx];
    unsigned int row  = idx >> 7;         // / 128 float4s per row
    unsigned int col4 = idx & 127u;
    *reinterpret_cast<f4*>(&lds[row * LDSW + col4 * 4u]) = v;
  }
  __syncthreads();

  // ---- Emit: 63 patches * 64 float4s = 4032 float4s.
  // out float4 index = ((b*NP + ph*63 + pw)*CC + c)*64 + (i*4 + j4)
  f4* dst = reinterpret_cast<f4*>(out) +
            (((size_t)b * NP + (size_t)ph * NW) * CC + c) * 64u;
  for (unsigned int u = tid; u < NW * 64u; u += 256u) {
    unsigned int pw = u >> 6;         // patch column
    unsigned int r  = u & 63u;        // i*4 + j4 within patch
    unsigned int i  = r >> 2;
    unsigned int j4 = r & 3u;
    f4 v = *reinterpret_cast<const f4*>(&lds[i * LDSW + pw * STR + j4 * 4u]);
    __builtin_nontemporal_store(v, &dst[(size_t)pw * (CC * 64u) + r]);
  }
}

extern "C" void kernel_launch(void* const* d_in, const int* in_sizes, int n_in,
                              void* d_out, int out_size, void* d_ws, size_t ws_size,
                              hipStream_t stream) {
  const float* x = (const float*)d_in[0];
  float* out = (float*)d_out;
  dim3 grid(BB * CC * NH);  // 3024 blocks
  extract_patches_lds<<<grid, 256, 0, stream>>>(x, out);
}